// Round 17
// baseline (44.821 us; speedup 1.0000x reference)
//
#include <hip/hip_runtime.h>

#define A_N 192
#define D_N 576
#define W_N 384
#define NPIX (W_N * W_N)   // 147456
#define NSIN (A_N * D_N)   // 110592
#define RSTR 580           // padded inter row stride (float2 units)

// ---- fused conv1+conv2 via on-demand boundary-class collapsed 9x9 kernels --
// (r14 body, unchanged). Writes inter[a*580+2+d] = (sino, sino_pred) with
// zero guard cells at d=-2,-1,576,577; block 0 fills tab[a]=(cb,sb,u,v).
__global__ __launch_bounds__(256, 1) void conv9_kernel(
    const float* __restrict__ sino, const float* __restrict__ angles,
    const float* __restrict__ w1, const float* __restrict__ b1,
    const float* __restrict__ w2, const float* __restrict__ b2,
    float* __restrict__ sino_pred, float2* __restrict__ inter,
    float4* __restrict__ tab)
{
    __shared__ float t[16][40];            // zero-padded 8x32 tile + 4 halo
    __shared__ float sw1[400], sw2[400], sb1[16];
    __shared__ float K[625], wsb1[25];
    __shared__ float Wcs[9][81];           // on-demand class kernels
    __shared__ float biasc[9];

    int tid = threadIdx.x;
    int byi = blockIdx.x / 18;             // 576/32 = 18 tiles in x
    int bxi = blockIdx.x % 18;
    int y0 = byi * 8, x0 = bxi * 32;

    if (blockIdx.x == 0) {                 // per-angle table + guard cells
        if (tid < A_N) {
            float s, c;
            sincosf(angles[tid], &s, &c);
            tab[tid] = make_float4(c, s, fmaf(576.f, c, -287.5f * s),
                                         fmaf(576.f, s,  287.5f * c));
        }
        for (int i = tid; i < A_N * 4; i += 256) {
            int a = i >> 2, j = i & 3;
            inter[a * RSTR + (j < 2 ? j : 576 + j)] = make_float2(0.f, 0.f);
        }
    }

    for (int i = tid; i < 640; i += 256) {
        int r = i / 40, c = i - r * 40;
        int gy = y0 - 4 + r, gx = x0 - 4 + c;
        t[r][c] = (gy >= 0 && gy < A_N && gx >= 0 && gx < D_N)
                ? sino[gy * D_N + gx] : 0.f;
    }
    for (int i = tid; i < 400; i += 256) { sw1[i] = w1[i]; sw2[i] = w2[i]; }
    if (tid < 16) sb1[tid] = b1[tid];
    __syncthreads();

    for (int i = tid; i < 625; i += 256) {
        int q = i / 25, r = i - q * 25;
        float acc = 0.f;
        #pragma unroll
        for (int c = 0; c < 16; ++c)
            acc = fmaf(sw2[c * 25 + q], sw1[c * 25 + r], acc);
        K[i] = acc;
    }
    if (tid < 25) {
        float acc = 0.f;
        #pragma unroll
        for (int c = 0; c < 16; ++c) acc = fmaf(sw2[c * 25 + tid], sb1[c], acc);
        wsb1[tid] = acc;
    }
    __syncthreads();

    int ylo = (y0 == 0) ? 0 : 2, yhi = (y0 == A_N - 8) ? 4 : 2;
    int xlo = (x0 == 0) ? 0 : 2, xhi = (x0 == D_N - 32) ? 4 : 2;
    int nx = xhi - xlo + 1;
    int nc = (yhi - ylo + 1) * nx;

    for (int e = tid; e < nc * 81; e += 256) {
        int ci = e / 81, s = e - ci * 81;
        int yc = ylo + ci / nx, xc = xlo + ci % nx;
        int sy = s / 9 - 4, sx = s % 9 - 4;
        float acc = 0.f;
        for (int qy = -2; qy <= 2; ++qy) {
            if ((yc == 0 && qy < 0) || (yc == 1 && qy < -1) ||
                (yc == 3 && qy > 1) || (yc == 4 && qy > 0)) continue;
            int vy = sy - qy; if (vy < -2 || vy > 2) continue;
            for (int qx = -2; qx <= 2; ++qx) {
                if ((xc == 0 && qx < 0) || (xc == 1 && qx < -1) ||
                    (xc == 3 && qx > 1) || (xc == 4 && qx > 0)) continue;
                int vx = sx - qx; if (vx < -2 || vx > 2) continue;
                acc += K[((qy + 2) * 5 + qx + 2) * 25 + (vy + 2) * 5 + (vx + 2)];
            }
        }
        Wcs[ci][s] = acc;
    }
    if (tid < nc) {
        int yc = ylo + tid / nx, xc = xlo + tid % nx;
        float acc = b2[0];
        for (int qy = -2; qy <= 2; ++qy) {
            if ((yc == 0 && qy < 0) || (yc == 1 && qy < -1) ||
                (yc == 3 && qy > 1) || (yc == 4 && qy > 0)) continue;
            for (int qx = -2; qx <= 2; ++qx) {
                if ((xc == 0 && qx < 0) || (xc == 1 && qx < -1) ||
                    (xc == 3 && qx > 1) || (xc == 4 && qx > 0)) continue;
                acc += wsb1[(qy + 2) * 5 + qx + 2];
            }
        }
        biasc[tid] = acc;
    }
    __syncthreads();

    int lr = tid >> 5, lc = tid & 31;
    int gy = y0 + lr, gx = x0 + lc;
    int yc = (gy <= 1) ? gy : ((gy >= A_N - 2) ? (gy - (A_N - 5)) : 2);
    int xc = (gx <= 1) ? gx : ((gx >= D_N - 2) ? (gx - (D_N - 5)) : 2);
    int ci = (yc - ylo) * nx + (xc - xlo);
    float acc = biasc[ci];
    const float* Wp = Wcs[ci];
    #pragma unroll
    for (int sy = 0; sy < 9; ++sy)
        #pragma unroll
        for (int sx = 0; sx < 9; ++sx)
            acc = fmaf(t[lr + sy][lc + sx], Wp[sy * 9 + sx], acc);
    sino_pred[gy * D_N + gx] = acc;
    inter[gy * RSTR + 2 + gx] = make_float2(t[lr + 4][lc + 4], acc);
}

// ---- fused full-sum dual backprojection + conv3 ----------------------------
// Each block owns a 16x16 output tile but computes bp on the 18x18 halo tile
// (324 positions, 384 threads, last wave partially idle). Each active thread
// sums ALL 192 angles (no seg split): one geometry chain + one float4 gather
// per angle covers both sinograms (r14 inner loop, byte-identical math).
// Halo positions outside the image are forced to 0 (conv3 zero-padding).
// Then conv3 runs in-block from LDS: writes img_sino + img_pred directly.
// The bp of the raw sino ("img") is consumed here and never hits global.
__global__ __launch_bounds__(384) void bpc3_kernel(
    const float2* __restrict__ inter, const float4* __restrict__ tab,
    const float* __restrict__ w3, const float* __restrict__ b3,
    float* __restrict__ img_sino, float* __restrict__ img_pred)
{
    __shared__ float t0s[18][19], t1s[18][19];
    __shared__ float sw[18];
    int tid = threadIdx.x;
    if (tid < 18) sw[tid] = w3[tid];
    if (tid < 324) {
        int r = tid / 18, c = tid - r * 18;
        int gy = blockIdx.y * 16 - 1 + r;
        int gx = blockIdx.x * 16 - 1 + c;
        float X = (float)gx - 191.5f;
        float Y = (float)gy - 191.5f;
        float acc0 = 0.f, acc1 = 0.f;
        const float2* base = inter + 2;
        #pragma unroll 8
        for (int a = 0; a < A_N; ++a) {
            float4 tb = tab[a];            // uniform -> scalar loads
            float den = fmaf(tb.x, Y, fmaf(-tb.y, X, 576.f));
            float num = fmaf(tb.z, X, fmaf(tb.w, Y, 165600.f));
            float s   = num * __builtin_amdgcn_rcpf(den);
            float sc  = fminf(fmaxf(s, -2.f), 576.f);   // v_med3_f32
            float fl  = floorf(sc);
            float fr  = sc - fl;
            int   ic  = (int)fl;
            float4 v = *reinterpret_cast<const float4*>(base + (size_t)a * RSTR + ic);
            float w0 = 1.f - fr;
            acc0 = fmaf(v.x, w0, fmaf(v.z, fr, acc0));
            acc1 = fmaf(v.y, w0, fmaf(v.w, fr, acc1));
        }
        bool inside = (gy >= 0 && gy < W_N && gx >= 0 && gx < W_N);
        t0s[r][c] = inside ? acc0 : 0.f;
        t1s[r][c] = inside ? acc1 : 0.f;
    }
    __syncthreads();
    if (tid < 256) {
        int lr = tid >> 4, lc = tid & 15;
        int gy = blockIdx.y * 16 + lr;
        int gx = blockIdx.x * 16 + lc;
        int g = gy * W_N + gx;
        img_sino[g] = t1s[lr + 1][lc + 1];
        float acc = b3[0];
        #pragma unroll
        for (int dy = 0; dy < 3; ++dy)
            #pragma unroll
            for (int dx = 0; dx < 3; ++dx) {
                acc = fmaf(t0s[lr + dy][lc + dx], sw[dy * 3 + dx], acc);
                acc = fmaf(t1s[lr + dy][lc + dx], sw[9 + dy * 3 + dx], acc);
            }
        img_pred[g] = acc;
    }
}

extern "C" void kernel_launch(void* const* d_in, const int* in_sizes, int n_in,
                              void* d_out, int out_size, void* d_ws, size_t ws_size,
                              hipStream_t stream) {
    const float* sino   = (const float*)d_in[0];
    const float* angles = (const float*)d_in[1];
    const float* w1     = (const float*)d_in[2];
    const float* b1     = (const float*)d_in[3];
    const float* w2     = (const float*)d_in[4];
    const float* b2     = (const float*)d_in[5];
    const float* w3     = (const float*)d_in[6];
    const float* b3     = (const float*)d_in[7];

    float* out       = (float*)d_out;
    float* sino_pred = out;                       // 110592
    float* img_sino  = out + NSIN;                // 147456
    float* img_pred  = img_sino + NPIX;           // 147456

    float2* inter = (float2*)d_ws;                          // 192*580 float2
    float4* tab   = (float4*)((char*)d_ws + (size_t)A_N * RSTR * sizeof(float2));

    conv9_kernel<<<dim3(432), dim3(256), 0, stream>>>(
        sino, angles, w1, b1, w2, b2, sino_pred, inter, tab);
    bpc3_kernel<<<dim3(24, 24), dim3(384), 0, stream>>>(
        inter, tab, w3, b3, img_sino, img_pred);
}

// Round 18
// 34.245 us; speedup vs baseline: 1.3089x; 1.3089x over previous
//
#include <hip/hip_runtime.h>

#define A_N 192
#define D_N 576
#define W_N 384
#define NPIX (W_N * W_N)   // 147456
#define NSIN (A_N * D_N)   // 110592
#define RSTR 580           // padded inter row stride (float2 units)

// ---- fused conv1+conv2 via on-demand boundary-class collapsed 9x9 kernels --
// (r14 body, unchanged). Writes inter[a*580+2+d] = (sino, sino_pred) with
// zero guard cells at d=-2,-1,576,577; block 0 fills tab[a]=(cb,sb,u,v).
__global__ __launch_bounds__(256, 1) void conv9_kernel(
    const float* __restrict__ sino, const float* __restrict__ angles,
    const float* __restrict__ w1, const float* __restrict__ b1,
    const float* __restrict__ w2, const float* __restrict__ b2,
    float* __restrict__ sino_pred, float2* __restrict__ inter,
    float4* __restrict__ tab)
{
    __shared__ float t[16][40];            // zero-padded 8x32 tile + 4 halo
    __shared__ float sw1[400], sw2[400], sb1[16];
    __shared__ float K[625], wsb1[25];
    __shared__ float Wcs[9][81];           // on-demand class kernels
    __shared__ float biasc[9];

    int tid = threadIdx.x;
    int byi = blockIdx.x / 18;             // 576/32 = 18 tiles in x
    int bxi = blockIdx.x % 18;
    int y0 = byi * 8, x0 = bxi * 32;

    if (blockIdx.x == 0) {                 // per-angle table + guard cells
        if (tid < A_N) {
            float s, c;
            sincosf(angles[tid], &s, &c);
            tab[tid] = make_float4(c, s, fmaf(576.f, c, -287.5f * s),
                                         fmaf(576.f, s,  287.5f * c));
        }
        for (int i = tid; i < A_N * 4; i += 256) {
            int a = i >> 2, j = i & 3;
            inter[a * RSTR + (j < 2 ? j : 576 + j)] = make_float2(0.f, 0.f);
        }
    }

    for (int i = tid; i < 640; i += 256) {
        int r = i / 40, c = i - r * 40;
        int gy = y0 - 4 + r, gx = x0 - 4 + c;
        t[r][c] = (gy >= 0 && gy < A_N && gx >= 0 && gx < D_N)
                ? sino[gy * D_N + gx] : 0.f;
    }
    for (int i = tid; i < 400; i += 256) { sw1[i] = w1[i]; sw2[i] = w2[i]; }
    if (tid < 16) sb1[tid] = b1[tid];
    __syncthreads();

    for (int i = tid; i < 625; i += 256) {
        int q = i / 25, r = i - q * 25;
        float acc = 0.f;
        #pragma unroll
        for (int c = 0; c < 16; ++c)
            acc = fmaf(sw2[c * 25 + q], sw1[c * 25 + r], acc);
        K[i] = acc;
    }
    if (tid < 25) {
        float acc = 0.f;
        #pragma unroll
        for (int c = 0; c < 16; ++c) acc = fmaf(sw2[c * 25 + tid], sb1[c], acc);
        wsb1[tid] = acc;
    }
    __syncthreads();

    int ylo = (y0 == 0) ? 0 : 2, yhi = (y0 == A_N - 8) ? 4 : 2;
    int xlo = (x0 == 0) ? 0 : 2, xhi = (x0 == D_N - 32) ? 4 : 2;
    int nx = xhi - xlo + 1;
    int nc = (yhi - ylo + 1) * nx;

    for (int e = tid; e < nc * 81; e += 256) {
        int ci = e / 81, s = e - ci * 81;
        int yc = ylo + ci / nx, xc = xlo + ci % nx;
        int sy = s / 9 - 4, sx = s % 9 - 4;
        float acc = 0.f;
        for (int qy = -2; qy <= 2; ++qy) {
            if ((yc == 0 && qy < 0) || (yc == 1 && qy < -1) ||
                (yc == 3 && qy > 1) || (yc == 4 && qy > 0)) continue;
            int vy = sy - qy; if (vy < -2 || vy > 2) continue;
            for (int qx = -2; qx <= 2; ++qx) {
                if ((xc == 0 && qx < 0) || (xc == 1 && qx < -1) ||
                    (xc == 3 && qx > 1) || (xc == 4 && qx > 0)) continue;
                int vx = sx - qx; if (vx < -2 || vx > 2) continue;
                acc += K[((qy + 2) * 5 + qx + 2) * 25 + (vy + 2) * 5 + (vx + 2)];
            }
        }
        Wcs[ci][s] = acc;
    }
    if (tid < nc) {
        int yc = ylo + tid / nx, xc = xlo + tid % nx;
        float acc = b2[0];
        for (int qy = -2; qy <= 2; ++qy) {
            if ((yc == 0 && qy < 0) || (yc == 1 && qy < -1) ||
                (yc == 3 && qy > 1) || (yc == 4 && qy > 0)) continue;
            for (int qx = -2; qx <= 2; ++qx) {
                if ((xc == 0 && qx < 0) || (xc == 1 && qx < -1) ||
                    (xc == 3 && qx > 1) || (xc == 4 && qx > 0)) continue;
                acc += wsb1[(qy + 2) * 5 + qx + 2];
            }
        }
        biasc[tid] = acc;
    }
    __syncthreads();

    int lr = tid >> 5, lc = tid & 31;
    int gy = y0 + lr, gx = x0 + lc;
    int yc = (gy <= 1) ? gy : ((gy >= A_N - 2) ? (gy - (A_N - 5)) : 2);
    int xc = (gx <= 1) ? gx : ((gx >= D_N - 2) ? (gx - (D_N - 5)) : 2);
    int ci = (yc - ylo) * nx + (xc - xlo);
    float acc = biasc[ci];
    const float* Wp = Wcs[ci];
    #pragma unroll
    for (int sy = 0; sy < 9; ++sy)
        #pragma unroll
        for (int sx = 0; sx < 9; ++sx)
            acc = fmaf(t[lr + sy][lc + sx], Wp[sy * 9 + sx], acc);
    sino_pred[gy * D_N + gx] = acc;
    inter[gy * RSTR + 2 + gx] = make_float2(t[lr + 4][lc + 4], acc);
}

// ---- dual fan-beam backprojection, 64x4 tiles (wave = 1 full row) ----------
// Same 1728-block / seg x3 shape as r14; ONLY the pixel->lane map changes:
// a wave's 64 lanes now cover 64 consecutive x of ONE row, so for each angle
// the gather addresses form a single contiguous detector span (~80 cells ~=
// 10-11 cache lines) instead of 4 separate clusters (~14-16 lines) -> fewer
// L1/TA transactions per gather instruction.
// part2 layout: [seg][NPIX] float2 = (img, img_sino) partial sums.
__global__ __launch_bounds__(256) void backproject2_kernel(
    const float2* __restrict__ inter, const float4* __restrict__ tab,
    float2* __restrict__ part2)
{
    int tid = threadIdx.x;
    int seg = blockIdx.z;                  // 0..2
    int a0 = seg * 64;
    int gx = blockIdx.x * 64 + (tid & 63);
    int gy = blockIdx.y * 4 + (tid >> 6);
    int idx = gy * W_N + gx;
    float X = (float)gx - 191.5f;
    float Y = (float)gy - 191.5f;
    float acc0 = 0.f, acc1 = 0.f;
    const float2* base = inter + (size_t)a0 * RSTR + 2;
    #pragma unroll 8
    for (int i = 0; i < 64; ++i) {
        float4 tb = tab[a0 + i];           // uniform -> scalar loads
        float den = fmaf(tb.x, Y, fmaf(-tb.y, X, 576.f));
        float num = fmaf(tb.z, X, fmaf(tb.w, Y, 165600.f));
        float s   = num * __builtin_amdgcn_rcpf(den);
        float sc  = fminf(fmaxf(s, -2.f), 576.f);   // v_med3_f32
        float fl  = floorf(sc);
        float fr  = sc - fl;
        int   ic  = (int)fl;
        float4 v = *reinterpret_cast<const float4*>(base + (size_t)i * RSTR + ic);
        acc0 = fmaf(v.x, 1.f - fr, fmaf(v.z, fr, acc0));
        acc1 = fmaf(v.y, 1.f - fr, fmaf(v.w, fr, acc1));
    }
    part2[seg * NPIX + idx] = make_float2(acc0, acc1);
}

// ---- fused partial-sum (x3) + conv3: writes img_sino and img_pred ----------
__global__ __launch_bounds__(256) void conv3_kernel(
    const float2* __restrict__ part2,
    const float* __restrict__ w3, const float* __restrict__ b3,
    float* __restrict__ img_sino, float* __restrict__ img_pred)
{
    __shared__ float t0[10][34], t1[10][34];
    __shared__ float sw[18];
    int tid = threadIdx.x;
    int byi = blockIdx.x / 12, bxi = blockIdx.x % 12;   // 384/32=12, 384/8=48
    int y0 = byi * 8, x0 = bxi * 32;
    for (int i = tid; i < 340; i += 256) {
        int r = i / 34, c = i - r * 34;
        int gy = y0 - 1 + r, gx = x0 - 1 + c;
        float s0 = 0.f, s1 = 0.f;
        if (gy >= 0 && gy < W_N && gx >= 0 && gx < W_N) {
            int g = gy * W_N + gx;
            #pragma unroll
            for (int p = 0; p < 3; ++p) {
                float2 v = part2[p * NPIX + g];
                s0 += v.x; s1 += v.y;
            }
        }
        t0[r][c] = s0; t1[r][c] = s1;
    }
    if (tid < 18) sw[tid] = w3[tid];
    __syncthreads();
    int lr = tid >> 5, lc = tid & 31;
    int gy = y0 + lr, gx = x0 + lc;
    int g = gy * W_N + gx;
    img_sino[g] = t1[lr + 1][lc + 1];
    float acc = b3[0];
    #pragma unroll
    for (int dy = 0; dy < 3; ++dy)
        #pragma unroll
        for (int dx = 0; dx < 3; ++dx) {
            acc = fmaf(t0[lr + dy][lc + dx], sw[dy * 3 + dx], acc);
            acc = fmaf(t1[lr + dy][lc + dx], sw[9 + dy * 3 + dx], acc);
        }
    img_pred[g] = acc;
}

extern "C" void kernel_launch(void* const* d_in, const int* in_sizes, int n_in,
                              void* d_out, int out_size, void* d_ws, size_t ws_size,
                              hipStream_t stream) {
    const float* sino   = (const float*)d_in[0];
    const float* angles = (const float*)d_in[1];
    const float* w1     = (const float*)d_in[2];
    const float* b1     = (const float*)d_in[3];
    const float* w2     = (const float*)d_in[4];
    const float* b2     = (const float*)d_in[5];
    const float* w3     = (const float*)d_in[6];
    const float* b3     = (const float*)d_in[7];

    float* out       = (float*)d_out;
    float* sino_pred = out;                       // 110592
    float* img_sino  = out + NSIN;                // 147456
    float* img_pred  = img_sino + NPIX;           // 147456

    float2* inter = (float2*)d_ws;                          // 192*580 float2
    float4* tab   = (float4*)((char*)d_ws + (size_t)A_N * RSTR * sizeof(float2));
    float2* part2 = (float2*)((char*)tab + A_N * sizeof(float4)); // 3*NPIX float2

    conv9_kernel<<<dim3(432), dim3(256), 0, stream>>>(
        sino, angles, w1, b1, w2, b2, sino_pred, inter, tab);
    backproject2_kernel<<<dim3(6, 96, 3), dim3(256), 0, stream>>>(
        inter, tab, part2);
    conv3_kernel<<<dim3(576), dim3(256), 0, stream>>>(
        part2, w3, b3, img_sino, img_pred);
}